// Round 21
// baseline (139.762 us; speedup 1.0000x reference)
//
#include <hip/hip_runtime.h>
#include <hip/hip_bf16.h>

// Problem constants
#define NB  2      // batch
#define CC  256    // channels
#define NHD 8      // heads
#define HD  32     // head dim
#define NT  4096   // tokens = H*W

typedef __bf16 bf16x8 __attribute__((ext_vector_type(8)));
typedef bf16x8 bf16x8_ma __attribute__((may_alias));
typedef __bf16 bf16x4 __attribute__((ext_vector_type(4)));
typedef bf16x4 bf16x4_ma __attribute__((may_alias));
typedef float  f32x4  __attribute__((ext_vector_type(4)));
typedef f32x4  f32x4_ma __attribute__((may_alias));
typedef float  f32x16 __attribute__((ext_vector_type(16)));
typedef unsigned int u32x4 __attribute__((ext_vector_type(4)));
typedef unsigned short u16x8 __attribute__((ext_vector_type(8)));

static __device__ __forceinline__ f32x4 zero4() {
    f32x4 z = {0.f, 0.f, 0.f, 0.f}; return z;
}
static __device__ __forceinline__ f32x16 zero16() {
    f32x16 z = {0.f,0.f,0.f,0.f,0.f,0.f,0.f,0.f,
                0.f,0.f,0.f,0.f,0.f,0.f,0.f,0.f};
    return z;
}
// Load 8 consecutive f32 and convert to bf16x8 (same rounding as convw_k).
static __device__ __forceinline__ bf16x8 ldcvt8(const float* __restrict__ p) {
    f32x4 lo = *(const f32x4_ma*)p;
    f32x4 hi = *(const f32x4_ma*)(p + 4);
    bf16x8 r;
#pragma unroll
    for (int i = 0; i < 4; ++i) { r[i] = (__bf16)lo[i]; r[4 + i] = (__bf16)hi[i]; }
    return r;
}

// q pre-scale: log2(e) / sqrt(32)
#define QSCALE 0.25505392421795654f

// v_cvt_pk_bf16_f32: dst.lo = bf16(lo), dst.hi = bf16(hi)  (no builtin on gfx950)
#define CVT_PK(dst, lo, hi_) \
    asm("v_cvt_pk_bf16_f32 %0, %1, %2" : "=v"(dst) : "v"(lo), "v"(hi_))
// v_permlane32_swap_b32: x[32:63] <-> y[0:31]
#define PLSWAP(x, y) \
    asm("v_permlane32_swap_b32 %0, %1" : "+v"(x), "+v"(y))

// ---------------------------------------------------------------------------
// ROUND 38: R37 passed at 136.4 (best). The R22 redundant-read mechanism
// applied to its last two sites: (1) proj grid y=4 -> y=2 with 2 output
// passes (ao staging and prologues halved; 2-phase half-stage keeps the one
// prologue overlapped); (2) convw folded into qkv/proj -- weights loaded f32
// and converted in-register during the latency-hidden A-preload (identical
// rounding; weights L2-resident). One kernel launch removed.
// attn (R33), comb unchanged.
// ---------------------------------------------------------------------------

// ---------------------------------------------------------------------------
// Kernel 2: QKV GEMM (MFMA), fused transpose staging, x staged ONCE per
// 64-token tile, 3 output passes of 64 o each (192 o per block).
// Weights read f32 + in-register cvt (convw folded in).
// grid (NT/64, 4, NB), block 256. LDS 33.8 KB.
// ---------------------------------------------------------------------------
__global__ __launch_bounds__(256) void qkv_k(const float* __restrict__ wqkv,
                                             const float* __restrict__ x,
                                             __bf16* __restrict__ qt,
                                             __bf16* __restrict__ kt,
                                             __bf16* __restrict__ vv) {
    __shared__ __align__(16) __bf16 T[64][264];   // [tok][c+pad] 33792 B

    const int tid  = threadIdx.x;
    const int lane = tid & 63, wv = tid >> 6;
    const int g = lane >> 4, c16 = lane & 15;
    const int b     = blockIdx.z;
    const int obase = blockIdx.y * 192;        // this block: o in [obase, obase+192)
    const int tok0  = blockIdx.x * 64;

    const int tok4 = (tid & 15) * 4;
    const int crow = tid >> 4;                 // 0..15

// Epilogue for one 64-o pass: acc[js] holds tok js*16+c16, o = o0p + g*4 + r.
#define QKV_EPI(o0p, accv) do {                                                         \
    const int reg = (o0p) >> 8;                                                         \
    const int oo0 = ((o0p) & 255) + g * 4;                                              \
    const int h   = oo0 >> 5;                                                           \
    const int dd0 = oo0 & 31;                                                           \
    const size_t bh = (size_t)(b * NHD + h);                                            \
    _Pragma("unroll")                                                                   \
    for (int js = 0; js < 4; ++js) {                                                    \
        const int tok = tok0 + js * 16 + c16;                                           \
        if (reg == 0) {                                                                 \
            bf16x4 pk;                                                                  \
            _Pragma("unroll")                                                           \
            for (int r = 0; r < 4; ++r) pk[r] = (__bf16)(accv[js][r] * QSCALE);         \
            *(bf16x4_ma*)(qt + (bh * NT + tok) * HD + dd0) = pk;                        \
        } else if (reg == 1) {                                                          \
            bf16x4 pk;                                                                  \
            _Pragma("unroll")                                                           \
            for (int r = 0; r < 4; ++r) pk[r] = (__bf16)accv[js][r];                    \
            *(bf16x4_ma*)(kt + (bh * NT + tok) * HD + dd0) = pk;                        \
        } else {                                                                        \
            _Pragma("unroll")                                                           \
            for (int r = 0; r < 4; ++r)                                                 \
                vv[(bh * HD + dd0 + r) * NT + tok] = (__bf16)accv[js][r];               \
        }                                                                               \
    }                                                                                   \
} while (0)

    // Phase A stage: half 0 (c in [0,128)) load+cvt+write.
    {
#pragma unroll
        for (int i = 0; i < 8; ++i) {
            const int c = i * 16 + crow;
            f32x4 v = *(const f32x4_ma*)&x[((size_t)(b * CC + c)) * NT + tok0 + tok4];
#pragma unroll
            for (int j = 0; j < 4; ++j) T[tok4 + j][c] = (__bf16)v[j];
        }
    }

    // Issue half-1 loads early (held in regs; consumed after first compute).
    f32x4 v1[8];
#pragma unroll
    for (int i = 0; i < 8; ++i) {
        const int c = 128 + i * 16 + crow;
        v1[i] = *(const f32x4_ma*)&x[((size_t)(b * CC + c)) * NT + tok0 + tok4];
    }

    // Preload A rows for pass 0 (f32 -> bf16 in-register).
    const float* arow0 = wqkv + (size_t)(obase + wv * 16 + c16) * CC + g * 8;
    bf16x8 a[8];
#pragma unroll
    for (int kc = 0; kc < 8; ++kc) a[kc] = ldcvt8(arow0 + kc * 32);

    __syncthreads();   // half 0 visible

    f32x4 acc[4];
#pragma unroll
    for (int i = 0; i < 4; ++i) acc[i] = zero4();

#pragma unroll
    for (int kc = 0; kc < 4; ++kc) {
#pragma unroll
        for (int js = 0; js < 4; ++js) {
            bf16x8 bb = *(const bf16x8_ma*)&T[js * 16 + c16][kc * 32 + g * 8];
            acc[js] = __builtin_amdgcn_mfma_f32_16x16x32_bf16(a[kc], bb, acc[js], 0, 0, 0);
        }
    }

    // Write half 1 (v1 already in regs).
#pragma unroll
    for (int i = 0; i < 8; ++i) {
        const int c = 128 + i * 16 + crow;
#pragma unroll
        for (int j = 0; j < 4; ++j) T[tok4 + j][c] = (__bf16)v1[i][j];
    }
    __syncthreads();   // half 1 visible

#pragma unroll
    for (int kc = 4; kc < 8; ++kc) {
#pragma unroll
        for (int js = 0; js < 4; ++js) {
            bf16x8 bb = *(const bf16x8_ma*)&T[js * 16 + c16][kc * 32 + g * 8];
            acc[js] = __builtin_amdgcn_mfma_f32_16x16x32_bf16(a[kc], bb, acc[js], 0, 0, 0);
        }
    }
    QKV_EPI(obase + wv * 16, acc);

    // Passes 1 and 2: full tile already in LDS.
#pragma unroll 1
    for (int pass = 1; pass < 3; ++pass) {
        const int o0p = obase + pass * 64 + wv * 16;
        const float* arow = wqkv + (size_t)(o0p + c16) * CC + g * 8;
#pragma unroll
        for (int kc = 0; kc < 8; ++kc) a[kc] = ldcvt8(arow + kc * 32);
#pragma unroll
        for (int i = 0; i < 4; ++i) acc[i] = zero4();
#pragma unroll
        for (int kc = 0; kc < 8; ++kc) {
#pragma unroll
            for (int js = 0; js < 4; ++js) {
                bf16x8 bb = *(const bf16x8_ma*)&T[js * 16 + c16][kc * 32 + g * 8];
                acc[js] = __builtin_amdgcn_mfma_f32_16x16x32_bf16(a[kc], bb, acc[js], 0, 0, 0);
            }
        }
        QKV_EPI(o0p, acc);
    }
#undef QKV_EPI
}

// ---------------------------------------------------------------------------
// Kernel 3: MFMA flash attention (R33 proven form, exact). 32x32 swapped-
// operand, in-register P, block-shared LDS K/V (2-phase), 128-j tiles,
// l on the MFMA pipe (ones-B). Block 256 = 4 waves x 32 q = 128 q/block.
// nseg>1: f32 partial (O,l) to PO/PL; nseg=1: ao directly.
// grid (NT/128, NB*NHD, JSEG), LDS 32KB.
// ---------------------------------------------------------------------------
__global__ __launch_bounds__(256, 4) void attn_k(const __bf16* __restrict__ qt,
                                                 const __bf16* __restrict__ kt,
                                                 const __bf16* __restrict__ vv,
                                                 __bf16* __restrict__ ao,
                                                 float* __restrict__ PO,
                                                 float* __restrict__ PL) {
    // Fragment lane-order tiles: [buf][js][half][lane*8 bf16]
    __shared__ __align__(16) __bf16 KF[2][4][2][512];   // 16 KB
    __shared__ __align__(16) __bf16 VF[2][4][2][512];   // 16 KB

    const int tid  = threadIdx.x;
    const int lane = tid & 63, wv = tid >> 6;          // wv 0..3
    const int c32 = lane & 31, hi = lane >> 5;
    const int bh = blockIdx.y;
    const int b = bh >> 3, h = bh & 7;
    const int seg = blockIdx.z, nseg = gridDim.z;
    const int i0q = blockIdx.x * 128 + wv * 32;        // this wave: 32 queries

    const __bf16* qbase = qt + ((size_t)bh * NT + i0q) * HD;
    const __bf16* kbase = kt + (size_t)bh * NT * HD;
    const __bf16* vbase = vv + (size_t)bh * HD * NT;

    // Q fragments (B operand of score MFMA): row=q=c32, k = kk*16 + hi*8 + e
    bf16x8 aq0 = *(const bf16x8_ma*)(qbase + (size_t)c32 * HD + hi * 8);
    bf16x8 aq1 = *(const bf16x8_ma*)(qbase + (size_t)c32 * HD + 16 + hi * 8);

    // All-ones bf16 B operand (layout-independent: every element is 1.0).
    u16x8 ones_u = {0x3F80,0x3F80,0x3F80,0x3F80,0x3F80,0x3F80,0x3F80,0x3F80};
    const bf16x8 ones = __builtin_bit_cast(bf16x8, ones_u);

    f32x16 oacc = zero16();      // D[q_row][d_col]: rows=q, cols=d=c32
    f32x16 lacc = zero16();      // row-sums of P, replicated across cols

// Stage one 128-j tile: wave wv stages its js=wv subtile of K and V (4 x 1KB).
#define STAGE(bf, jb) do {                                                              \
    const __bf16* gk = kbase + (size_t)((jb) + wv * 32 + c32) * HD + hi * 8;            \
    __builtin_amdgcn_global_load_lds(                                                   \
        (const __attribute__((address_space(1))) void*)gk,                              \
        (__attribute__((address_space(3))) void*)&KF[bf][wv][0][0],                     \
        16, 0, 0);                                                                      \
    __builtin_amdgcn_global_load_lds(                                                   \
        (const __attribute__((address_space(1))) void*)(gk + 16),                       \
        (__attribute__((address_space(3))) void*)&KF[bf][wv][1][0],                     \
        16, 0, 0);                                                                      \
    const __bf16* gv = vbase + (size_t)c32 * NT + (jb) + wv * 32 + hi * 8;              \
    __builtin_amdgcn_global_load_lds(                                                   \
        (const __attribute__((address_space(1))) void*)gv,                              \
        (__attribute__((address_space(3))) void*)&VF[bf][wv][0][0],                     \
        16, 0, 0);                                                                      \
    __builtin_amdgcn_global_load_lds(                                                   \
        (const __attribute__((address_space(1))) void*)(gv + 16),                       \
        (__attribute__((address_space(3))) void*)&VF[bf][wv][1][0],                     \
        16, 0, 0);                                                                      \
} while (0)

#define SUBTILE(bf, js) do {                                                            \
    bf16x8 fk0 = *(const bf16x8_ma*)&KF[bf][js][0][lane * 8];                           \
    bf16x8 fk1 = *(const bf16x8_ma*)&KF[bf][js][1][lane * 8];                           \
    bf16x8 fv0 = *(const bf16x8_ma*)&VF[bf][js][0][lane * 8];                           \
    bf16x8 fv1 = *(const bf16x8_ma*)&VF[bf][js][1][lane * 8];                           \
    f32x16 s = __builtin_amdgcn_mfma_f32_32x32x16_bf16(fk0, aq0, zero16(), 0, 0, 0);    \
    s = __builtin_amdgcn_mfma_f32_32x32x16_bf16(fk1, aq1, s, 0, 0, 0);                  \
    float p[16];                                                                        \
    _Pragma("unroll")                                                                   \
    for (int r = 0; r < 16; ++r) p[r] = __builtin_amdgcn_exp2f(s[r]);                   \
    unsigned pk[8];                                                                     \
    _Pragma("unroll")                                                                   \
    for (int i = 0; i < 8; ++i) CVT_PK(pk[i], p[2 * i], p[2 * i + 1]);                  \
    PLSWAP(pk[0], pk[2]);                                                               \
    PLSWAP(pk[1], pk[3]);                                                               \
    PLSWAP(pk[4], pk[6]);                                                               \
    PLSWAP(pk[5], pk[7]);                                                               \
    u32x4 a0 = {pk[0], pk[1], pk[2], pk[3]};                                            \
    u32x4 a1 = {pk[4], pk[5], pk[6], pk[7]};                                            \
    const bf16x8 ap0 = __builtin_bit_cast(bf16x8, a0);                                  \
    const bf16x8 ap1 = __builtin_bit_cast(bf16x8, a1);                                  \
    oacc = __builtin_amdgcn_mfma_f32_32x32x16_bf16(ap0, fv0, oacc, 0, 0, 0);            \
    oacc = __builtin_amdgcn_mfma_f32_32x32x16_bf16(ap1, fv1, oacc, 0, 0, 0);            \
    lacc = __builtin_amdgcn_mfma_f32_32x32x16_bf16(ap0, ones, lacc, 0, 0, 0);           \
    lacc = __builtin_amdgcn_mfma_f32_32x32x16_bf16(ap1, ones, lacc, 0, 0, 0);           \
} while (0)

    const int ntiles  = (NT / 128) / nseg;         // 16 @ jseg=2, 32 @ jseg=1
    const int j_begin = seg * ntiles * 128;

    // Prologue: stage tile 0 into buf 0.
    STAGE(0, j_begin);
    asm volatile("s_waitcnt vmcnt(0)" ::: "memory");
    __syncthreads();

    int buf = 0;
#pragma unroll 1
    for (int t = 0; t < ntiles; ++t) {
        if (t + 1 < ntiles) STAGE(buf ^ 1, j_begin + (t + 1) * 128);
        SUBTILE(buf, 0);
        SUBTILE(buf, 1);
        SUBTILE(buf, 2);
        SUBTILE(buf, 3);
        asm volatile("s_waitcnt vmcnt(0)" ::: "memory");
        __syncthreads();
        buf ^= 1;
    }

#undef STAGE
#undef SUBTILE

    if (nseg == 1) {
        // Direct epilogue: oacc/lacc rows q = 8*g4 + 4*hi + r, cols d = c32.
#pragma unroll
        for (int g4 = 0; g4 < 4; ++g4) {
#pragma unroll
            for (int r = 0; r < 4; ++r) {
                const int q = 8 * g4 + 4 * hi + r;
                ao[((size_t)(b * NT) + i0q + q) * CC + h * HD + c32] =
                    (__bf16)(oacc[4 * g4 + r] / lacc[4 * g4 + r]);
            }
        }
    } else {
        // Partial epilogue: PO [seg][bh][n][32] f32, PL [seg][bh][n] f32.
        float* po = PO + (((size_t)seg * NB * NHD + bh) * NT + i0q) * HD;
#pragma unroll
        for (int g4 = 0; g4 < 4; ++g4) {
#pragma unroll
            for (int r = 0; r < 4; ++r) {
                const int q = 8 * g4 + 4 * hi + r;
                po[(size_t)q * HD + c32] = oacc[4 * g4 + r];
            }
        }
        if (c32 == 0) {
            float* pl = PL + ((size_t)seg * NB * NHD + bh) * NT + i0q;
#pragma unroll
            for (int g4 = 0; g4 < 4; ++g4)
#pragma unroll
                for (int r = 0; r < 4; ++r)
                    pl[8 * g4 + 4 * hi + r] = lacc[4 * g4 + r];
        }
    }
}

// ---------------------------------------------------------------------------
// Kernel 3b: combine nseg partials: ao = (Sum O_s)/(Sum l_s), bf16.
// One thread = 4 consecutive d of one (bh, n). grid 2048 x 256.
// ---------------------------------------------------------------------------
__global__ __launch_bounds__(256) void comb_k(const float* __restrict__ PO,
                                              const float* __restrict__ PL,
                                              __bf16* __restrict__ ao,
                                              int nseg) {
    const int i = blockIdx.x * 256 + threadIdx.x;    // 0 .. 16*4096*8-1
    const int bh = i >> 15;                          // 8 groups * 4096 n
    const int rem = i & 32767;
    const int n = rem >> 3, g = rem & 7;
    const int b = bh >> 3, h = bh & 7;

    const size_t SEGO = (size_t)(NB * NHD) * NT * HD;
    const size_t SEGL = (size_t)(NB * NHD) * NT;
    const size_t o0i = (((size_t)bh) * NT + n) * HD + g * 4;
    const size_t li  = (size_t)bh * NT + n;

    f32x4 o = *(const f32x4_ma*)&PO[o0i];
    float l = PL[li];
#pragma unroll 3
    for (int s = 1; s < nseg; ++s) {
        o += *(const f32x4_ma*)&PO[(size_t)s * SEGO + o0i];
        l += PL[(size_t)s * SEGL + li];
    }

    bf16x4 pk;
#pragma unroll
    for (int r = 0; r < 4; ++r) pk[r] = (__bf16)(o[r] / l);
    *(bf16x4_ma*)&ao[((size_t)(b * NT) + n) * CC + h * HD + g * 4] = pk;
}

// ---------------------------------------------------------------------------
// Kernel 4: proj GEMM + residual, F32 output, B-tile LDS-shared 2-phase,
// ao staged ONCE per 128-o block, 2 output passes (R22 mechanism), early
// residual x-loads per pass, weights read f32 + in-register cvt.
// grid (NT/64, 2, NB), block 256. LDS 32 KB.
// ---------------------------------------------------------------------------
__global__ __launch_bounds__(256) void proj_k(const float* __restrict__ wp,
                                              const __bf16* __restrict__ ao,
                                              const float* __restrict__ x,
                                              float* __restrict__ out) {
    __shared__ __align__(16) __bf16 BF[4][8][512];   // [js][kc][lane*8] 32 KB

    const int lane = threadIdx.x & 63, wv = threadIdx.x >> 6;
    const int g = lane >> 4, c16 = lane & 15;
    const int b     = blockIdx.z;
    const int obase = blockIdx.y * 128;        // this block: o in [obase, obase+128)
    const int tok0  = blockIdx.x * 64;

    const __bf16* bsrc = ao + ((size_t)(b * NT + tok0 + wv * 16 + c16)) * CC + g * 8;
    // Stage half 0 (kc 0..3).
#pragma unroll
    for (int kc = 0; kc < 4; ++kc) {
        __builtin_amdgcn_global_load_lds(
            (const __attribute__((address_space(1))) void*)(bsrc + kc * 32),
            (__attribute__((address_space(3))) void*)&BF[wv][kc][0],
            16, 0, 0);
    }

    // Pass-0 A preload (f32 -> bf16) + residual x-loads (early, latency-hidden).
    const int o00 = obase + wv * 16;
    const float* arow = wp + (size_t)(o00 + c16) * CC + g * 8;
    bf16x8 a[8];
#pragma unroll
    for (int kc = 0; kc < 8; ++kc) a[kc] = ldcvt8(arow + kc * 32);

    float xres[4][4];
#pragma unroll
    for (int js = 0; js < 4; ++js) {
        const int tok = tok0 + js * 16 + c16;
#pragma unroll
        for (int r = 0; r < 4; ++r)
            xres[js][r] = x[((size_t)(b * CC + o00 + g * 4 + r)) * NT + tok];
    }

    __syncthreads();   // half 0 + A + x ready

    // Stage half 1 (kc 4..7) -- lands under the kc0..3 MFMAs.
#pragma unroll
    for (int kc = 4; kc < 8; ++kc) {
        __builtin_amdgcn_global_load_lds(
            (const __attribute__((address_space(1))) void*)(bsrc + kc * 32),
            (__attribute__((address_space(3))) void*)&BF[wv][kc][0],
            16, 0, 0);
    }

    f32x4 acc[4];
#pragma unroll
    for (int i = 0; i < 4; ++i) acc[i] = zero4();

#pragma unroll
    for (int kc = 0; kc < 4; ++kc) {
#pragma unroll
        for (int js = 0; js < 4; ++js) {
            bf16x8 bb = *(const bf16x8_ma*)&BF[js][kc][lane * 8];
            acc[js] = __builtin_amdgcn_mfma_f32_16x16x32_bf16(a[kc], bb, acc[js], 0, 0, 0);
        }
    }

    asm volatile("s_waitcnt vmcnt(0)" ::: "memory");
    __syncthreads();   // half 1 ready

#pragma unroll
    for (int kc = 4; kc < 8; ++kc) {
#pragma unroll
        for (int js = 0; js < 4; ++js) {
            bf16x8 bb = *(const bf16x8_ma*)&BF[js][kc][lane * 8];
            acc[js] = __builtin_amdgcn_mfma_f32_16x16x32_bf16(a[kc], bb, acc[js], 0, 0, 0);
        }
    }

    // Pass-0 epilogue.
#pragma unroll
    for (int js = 0; js < 4; ++js) {
        const int tok = tok0 + js * 16 + c16;
#pragma unroll
        for (int r = 0; r < 4; ++r) {
            const size_t idx = ((size_t)(b * CC + o00 + g * 4 + r)) * NT + tok;
            out[idx] = acc[js][r] + xres[js][r];
        }
    }

    // Pass 1: full tile already in LDS; new A rows + residuals.
    {
        const int o01 = obase + 64 + wv * 16;
        const float* arow1 = wp + (size_t)(o01 + c16) * CC + g * 8;
#pragma unroll
        for (int kc = 0; kc < 8; ++kc) a[kc] = ldcvt8(arow1 + kc * 32);
#pragma unroll
        for (int js = 0; js < 4; ++js) {
            const int tok = tok0 + js * 16 + c16;
#pragma unroll
            for (int r = 0; r < 4; ++r)
                xres[js][r] = x[((size_t)(b * CC + o01 + g * 4 + r)) * NT + tok];
        }
#pragma unroll
        for (int i = 0; i < 4; ++i) acc[i] = zero4();
#pragma unroll
        for (int kc = 0; kc < 8; ++kc) {
#pragma unroll
            for (int js = 0; js < 4; ++js) {
                bf16x8 bb = *(const bf16x8_ma*)&BF[js][kc][lane * 8];
                acc[js] = __builtin_amdgcn_mfma_f32_16x16x32_bf16(a[kc], bb, acc[js], 0, 0, 0);
            }
        }
#pragma unroll
        for (int js = 0; js < 4; ++js) {
            const int tok = tok0 + js * 16 + c16;
#pragma unroll
            for (int r = 0; r < 4; ++r) {
                const size_t idx = ((size_t)(b * CC + o01 + g * 4 + r)) * NT + tok;
                out[idx] = acc[js][r] + xres[js][r];
            }
        }
    }
}

// ---------------------------------------------------------------------------
extern "C" void kernel_launch(void* const* d_in, const int* in_sizes, int n_in,
                              void* d_out, int out_size, void* d_ws, size_t ws_size,
                              hipStream_t stream) {
    const int SX  = NB * CC * NT;   // 2,097,152
    const int SW3 = 3 * CC * CC;    //   196,608
    const int SW1 = CC * CC;        //    65,536
    const size_t E = (size_t)SX;

    const float* x  = nullptr;
    const float* wq = nullptr;
    const float* wp = nullptr;
    for (int i = 0; i < n_in; ++i) {
        const int sz = in_sizes[i];
        if (sz == SX || sz == 2 * SX || sz == 4 * SX)           x  = (const float*)d_in[i];
        else if (sz == SW3 || sz == 2 * SW3 || sz == 4 * SW3)   wq = (const float*)d_in[i];
        else if (sz == SW1 || sz == 2 * SW1 || sz == 4 * SW1)   wp = (const float*)d_in[i];
    }
    if (!x || !wq || !wp) {
        x  = (const float*)d_in[0];
        wq = (const float*)d_in[1];
        wp = (const float*)d_in[2];
    }

    // Workspace (bf16 elements): convw folded away; ao at base.
    __bf16* ws  = (__bf16*)d_ws;
    __bf16* ao  = ws;
    __bf16* qt  = ao + E;
    __bf16* kt  = qt + E;
    __bf16* vv  = kt + E;

    // Optional JSEG partial buffers (f32), appended after vv:
    const size_t baseB = 4 * E * 2;                                 // 16.8 MB
    const size_t segoB = (size_t)NB * NHD * NT * HD * 4;            // 8.39 MB/seg
    const size_t seglB = (size_t)NB * NHD * NT * 4;                 // 0.26 MB/seg
    const int jseg = (ws_size >= baseB + 2 * (segoB + seglB)) ? 2 : 1;
    float* PO = (float*)((char*)d_ws + baseB);
    float* PL = (float*)((char*)d_ws + baseB + (size_t)jseg * segoB);

    float* out = (float*)d_out;

    qkv_k<<<dim3(NT / 64, 4, NB), 256, 0, stream>>>(wq, x, qt, kt, vv);
    attn_k<<<dim3(NT / 128, NB * NHD, jseg), 256, 0, stream>>>(qt, kt, vv, ao, PO, PL);
    if (jseg > 1)
        comb_k<<<dim3((NB * NHD * NT * (HD / 4)) / 256), 256, 0, stream>>>(PO, PL, ao, jseg);
    proj_k<<<dim3(NT / 64, 2, NB), 256, 0, stream>>>(wp, ao, x, out);
}

// Round 22
// 135.835 us; speedup vs baseline: 1.0289x; 1.0289x over previous
//
#include <hip/hip_runtime.h>
#include <hip/hip_bf16.h>

// Problem constants
#define NB  2      // batch
#define CC  256    // channels
#define NHD 8      // heads
#define HD  32     // head dim
#define NT  4096   // tokens = H*W

typedef __bf16 bf16x8 __attribute__((ext_vector_type(8)));
typedef bf16x8 bf16x8_ma __attribute__((may_alias));
typedef __bf16 bf16x4 __attribute__((ext_vector_type(4)));
typedef bf16x4 bf16x4_ma __attribute__((may_alias));
typedef float  f32x4  __attribute__((ext_vector_type(4)));
typedef f32x4  f32x4_ma __attribute__((may_alias));
typedef float  f32x16 __attribute__((ext_vector_type(16)));
typedef unsigned int u32x4 __attribute__((ext_vector_type(4)));
typedef unsigned short u16x8 __attribute__((ext_vector_type(8)));

static __device__ __forceinline__ f32x4 zero4() {
    f32x4 z = {0.f, 0.f, 0.f, 0.f}; return z;
}
static __device__ __forceinline__ f32x16 zero16() {
    f32x16 z = {0.f,0.f,0.f,0.f,0.f,0.f,0.f,0.f,
                0.f,0.f,0.f,0.f,0.f,0.f,0.f,0.f};
    return z;
}

// q pre-scale: log2(e) / sqrt(32)
#define QSCALE 0.25505392421795654f

// v_cvt_pk_bf16_f32: dst.lo = bf16(lo), dst.hi = bf16(hi)  (no builtin on gfx950)
#define CVT_PK(dst, lo, hi_) \
    asm("v_cvt_pk_bf16_f32 %0, %1, %2" : "=v"(dst) : "v"(lo), "v"(hi_))
// v_permlane32_swap_b32: x[32:63] <-> y[0:31]
#define PLSWAP(x, y) \
    asm("v_permlane32_swap_b32 %0, %1" : "+v"(x), "+v"(y))

// ---------------------------------------------------------------------------
// ROUND 39: R38 (proj 2-pass + convw fold) REGRESSED 136.4 -> 139.8 (proj at
// 1 blk/CU lost latency hiding -- the R34 occupancy cliff; f32 weight loads
// doubled prologue bytes). Pre-committed null criterion triggered: revert to
// the R37 byte-proven optimum (136.4us). Configuration:
//  convw separate; qkv 3-pass y=4 (bf16 weights, fused transpose, 2-phase);
//  attn R33 (4-wave/32q, 128-j tiles, l on MFMA, JSEG=2); proj R35 (y=4,
//  2-phase + early x); comb JSEG combine.
// ---------------------------------------------------------------------------

// ---------------------------------------------------------------------------
// Kernel 0: f32 -> bf16 convert, both weight arrays in one launch.
// ---------------------------------------------------------------------------
__global__ __launch_bounds__(256) void convw_k(const float* __restrict__ s1,
                                               __bf16* __restrict__ d1, int n1,
                                               const float* __restrict__ s2,
                                               __bf16* __restrict__ d2, int n2) {
    const int i = blockIdx.x * 256 + threadIdx.x;
    if (i < n1) d1[i] = (__bf16)s1[i];
    else if (i - n1 < n2) d2[i - n1] = (__bf16)s2[i - n1];
}

// ---------------------------------------------------------------------------
// Kernel 2: QKV GEMM (MFMA), fused transpose staging, x staged ONCE per
// 64-token tile, 3 output passes of 64 o each (192 o per block).
// grid (NT/64, 4, NB), block 256. LDS 33.8 KB.
// ---------------------------------------------------------------------------
__global__ __launch_bounds__(256) void qkv_k(const __bf16* __restrict__ wqkv,
                                             const float* __restrict__ x,
                                             __bf16* __restrict__ qt,
                                             __bf16* __restrict__ kt,
                                             __bf16* __restrict__ vv) {
    __shared__ __align__(16) __bf16 T[64][264];   // [tok][c+pad] 33792 B

    const int tid  = threadIdx.x;
    const int lane = tid & 63, wv = tid >> 6;
    const int g = lane >> 4, c16 = lane & 15;
    const int b     = blockIdx.z;
    const int obase = blockIdx.y * 192;        // this block: o in [obase, obase+192)
    const int tok0  = blockIdx.x * 64;

    const int tok4 = (tid & 15) * 4;
    const int crow = tid >> 4;                 // 0..15

// Epilogue for one 64-o pass: acc[js] holds tok js*16+c16, o = o0p + g*4 + r.
#define QKV_EPI(o0p, accv) do {                                                         \
    const int reg = (o0p) >> 8;                                                         \
    const int oo0 = ((o0p) & 255) + g * 4;                                              \
    const int h   = oo0 >> 5;                                                           \
    const int dd0 = oo0 & 31;                                                           \
    const size_t bh = (size_t)(b * NHD + h);                                            \
    _Pragma("unroll")                                                                   \
    for (int js = 0; js < 4; ++js) {                                                    \
        const int tok = tok0 + js * 16 + c16;                                           \
        if (reg == 0) {                                                                 \
            bf16x4 pk;                                                                  \
            _Pragma("unroll")                                                           \
            for (int r = 0; r < 4; ++r) pk[r] = (__bf16)(accv[js][r] * QSCALE);         \
            *(bf16x4_ma*)(qt + (bh * NT + tok) * HD + dd0) = pk;                        \
        } else if (reg == 1) {                                                          \
            bf16x4 pk;                                                                  \
            _Pragma("unroll")                                                           \
            for (int r = 0; r < 4; ++r) pk[r] = (__bf16)accv[js][r];                    \
            *(bf16x4_ma*)(kt + (bh * NT + tok) * HD + dd0) = pk;                        \
        } else {                                                                        \
            _Pragma("unroll")                                                           \
            for (int r = 0; r < 4; ++r)                                                 \
                vv[(bh * HD + dd0 + r) * NT + tok] = (__bf16)accv[js][r];               \
        }                                                                               \
    }                                                                                   \
} while (0)

    // Phase A stage: half 0 (c in [0,128)) load+cvt+write.
    {
#pragma unroll
        for (int i = 0; i < 8; ++i) {
            const int c = i * 16 + crow;
            f32x4 v = *(const f32x4_ma*)&x[((size_t)(b * CC + c)) * NT + tok0 + tok4];
#pragma unroll
            for (int j = 0; j < 4; ++j) T[tok4 + j][c] = (__bf16)v[j];
        }
    }

    // Issue half-1 loads early (held in regs; consumed after first compute).
    f32x4 v1[8];
#pragma unroll
    for (int i = 0; i < 8; ++i) {
        const int c = 128 + i * 16 + crow;
        v1[i] = *(const f32x4_ma*)&x[((size_t)(b * CC + c)) * NT + tok0 + tok4];
    }

    // Preload A rows for pass 0.
    const __bf16* arow0 = wqkv + (size_t)(obase + wv * 16 + c16) * CC + g * 8;
    bf16x8 a[8];
#pragma unroll
    for (int kc = 0; kc < 8; ++kc) a[kc] = *(const bf16x8_ma*)(arow0 + kc * 32);

    __syncthreads();   // half 0 visible

    f32x4 acc[4];
#pragma unroll
    for (int i = 0; i < 4; ++i) acc[i] = zero4();

#pragma unroll
    for (int kc = 0; kc < 4; ++kc) {
#pragma unroll
        for (int js = 0; js < 4; ++js) {
            bf16x8 bb = *(const bf16x8_ma*)&T[js * 16 + c16][kc * 32 + g * 8];
            acc[js] = __builtin_amdgcn_mfma_f32_16x16x32_bf16(a[kc], bb, acc[js], 0, 0, 0);
        }
    }

    // Write half 1 (v1 already in regs).
#pragma unroll
    for (int i = 0; i < 8; ++i) {
        const int c = 128 + i * 16 + crow;
#pragma unroll
        for (int j = 0; j < 4; ++j) T[tok4 + j][c] = (__bf16)v1[i][j];
    }
    __syncthreads();   // half 1 visible

#pragma unroll
    for (int kc = 4; kc < 8; ++kc) {
#pragma unroll
        for (int js = 0; js < 4; ++js) {
            bf16x8 bb = *(const bf16x8_ma*)&T[js * 16 + c16][kc * 32 + g * 8];
            acc[js] = __builtin_amdgcn_mfma_f32_16x16x32_bf16(a[kc], bb, acc[js], 0, 0, 0);
        }
    }
    QKV_EPI(obase + wv * 16, acc);

    // Passes 1 and 2: full tile already in LDS.
#pragma unroll 1
    for (int pass = 1; pass < 3; ++pass) {
        const int o0p = obase + pass * 64 + wv * 16;
        const __bf16* arow = wqkv + (size_t)(o0p + c16) * CC + g * 8;
#pragma unroll
        for (int kc = 0; kc < 8; ++kc) a[kc] = *(const bf16x8_ma*)(arow + kc * 32);
#pragma unroll
        for (int i = 0; i < 4; ++i) acc[i] = zero4();
#pragma unroll
        for (int kc = 0; kc < 8; ++kc) {
#pragma unroll
            for (int js = 0; js < 4; ++js) {
                bf16x8 bb = *(const bf16x8_ma*)&T[js * 16 + c16][kc * 32 + g * 8];
                acc[js] = __builtin_amdgcn_mfma_f32_16x16x32_bf16(a[kc], bb, acc[js], 0, 0, 0);
            }
        }
        QKV_EPI(o0p, acc);
    }
#undef QKV_EPI
}

// ---------------------------------------------------------------------------
// Kernel 3: MFMA flash attention (R33 proven form, exact). 32x32 swapped-
// operand, in-register P, block-shared LDS K/V (2-phase), 128-j tiles,
// l on the MFMA pipe (ones-B). Block 256 = 4 waves x 32 q = 128 q/block.
// nseg>1: f32 partial (O,l) to PO/PL; nseg=1: ao directly.
// grid (NT/128, NB*NHD, JSEG), LDS 32KB.
// ---------------------------------------------------------------------------
__global__ __launch_bounds__(256, 4) void attn_k(const __bf16* __restrict__ qt,
                                                 const __bf16* __restrict__ kt,
                                                 const __bf16* __restrict__ vv,
                                                 __bf16* __restrict__ ao,
                                                 float* __restrict__ PO,
                                                 float* __restrict__ PL) {
    // Fragment lane-order tiles: [buf][js][half][lane*8 bf16]
    __shared__ __align__(16) __bf16 KF[2][4][2][512];   // 16 KB
    __shared__ __align__(16) __bf16 VF[2][4][2][512];   // 16 KB

    const int tid  = threadIdx.x;
    const int lane = tid & 63, wv = tid >> 6;          // wv 0..3
    const int c32 = lane & 31, hi = lane >> 5;
    const int bh = blockIdx.y;
    const int b = bh >> 3, h = bh & 7;
    const int seg = blockIdx.z, nseg = gridDim.z;
    const int i0q = blockIdx.x * 128 + wv * 32;        // this wave: 32 queries

    const __bf16* qbase = qt + ((size_t)bh * NT + i0q) * HD;
    const __bf16* kbase = kt + (size_t)bh * NT * HD;
    const __bf16* vbase = vv + (size_t)bh * HD * NT;

    // Q fragments (B operand of score MFMA): row=q=c32, k = kk*16 + hi*8 + e
    bf16x8 aq0 = *(const bf16x8_ma*)(qbase + (size_t)c32 * HD + hi * 8);
    bf16x8 aq1 = *(const bf16x8_ma*)(qbase + (size_t)c32 * HD + 16 + hi * 8);

    // All-ones bf16 B operand (layout-independent: every element is 1.0).
    u16x8 ones_u = {0x3F80,0x3F80,0x3F80,0x3F80,0x3F80,0x3F80,0x3F80,0x3F80};
    const bf16x8 ones = __builtin_bit_cast(bf16x8, ones_u);

    f32x16 oacc = zero16();      // D[q_row][d_col]: rows=q, cols=d=c32
    f32x16 lacc = zero16();      // row-sums of P, replicated across cols

// Stage one 128-j tile: wave wv stages its js=wv subtile of K and V (4 x 1KB).
#define STAGE(bf, jb) do {                                                              \
    const __bf16* gk = kbase + (size_t)((jb) + wv * 32 + c32) * HD + hi * 8;            \
    __builtin_amdgcn_global_load_lds(                                                   \
        (const __attribute__((address_space(1))) void*)gk,                              \
        (__attribute__((address_space(3))) void*)&KF[bf][wv][0][0],                     \
        16, 0, 0);                                                                      \
    __builtin_amdgcn_global_load_lds(                                                   \
        (const __attribute__((address_space(1))) void*)(gk + 16),                       \
        (__attribute__((address_space(3))) void*)&KF[bf][wv][1][0],                     \
        16, 0, 0);                                                                      \
    const __bf16* gv = vbase + (size_t)c32 * NT + (jb) + wv * 32 + hi * 8;              \
    __builtin_amdgcn_global_load_lds(                                                   \
        (const __attribute__((address_space(1))) void*)gv,                              \
        (__attribute__((address_space(3))) void*)&VF[bf][wv][0][0],                     \
        16, 0, 0);                                                                      \
    __builtin_amdgcn_global_load_lds(                                                   \
        (const __attribute__((address_space(1))) void*)(gv + 16),                       \
        (__attribute__((address_space(3))) void*)&VF[bf][wv][1][0],                     \
        16, 0, 0);                                                                      \
} while (0)

#define SUBTILE(bf, js) do {                                                            \
    bf16x8 fk0 = *(const bf16x8_ma*)&KF[bf][js][0][lane * 8];                           \
    bf16x8 fk1 = *(const bf16x8_ma*)&KF[bf][js][1][lane * 8];                           \
    bf16x8 fv0 = *(const bf16x8_ma*)&VF[bf][js][0][lane * 8];                           \
    bf16x8 fv1 = *(const bf16x8_ma*)&VF[bf][js][1][lane * 8];                           \
    f32x16 s = __builtin_amdgcn_mfma_f32_32x32x16_bf16(fk0, aq0, zero16(), 0, 0, 0);    \
    s = __builtin_amdgcn_mfma_f32_32x32x16_bf16(fk1, aq1, s, 0, 0, 0);                  \
    float p[16];                                                                        \
    _Pragma("unroll")                                                                   \
    for (int r = 0; r < 16; ++r) p[r] = __builtin_amdgcn_exp2f(s[r]);                   \
    unsigned pk[8];                                                                     \
    _Pragma("unroll")                                                                   \
    for (int i = 0; i < 8; ++i) CVT_PK(pk[i], p[2 * i], p[2 * i + 1]);                  \
    PLSWAP(pk[0], pk[2]);                                                               \
    PLSWAP(pk[1], pk[3]);                                                               \
    PLSWAP(pk[4], pk[6]);                                                               \
    PLSWAP(pk[5], pk[7]);                                                               \
    u32x4 a0 = {pk[0], pk[1], pk[2], pk[3]};                                            \
    u32x4 a1 = {pk[4], pk[5], pk[6], pk[7]};                                            \
    const bf16x8 ap0 = __builtin_bit_cast(bf16x8, a0);                                  \
    const bf16x8 ap1 = __builtin_bit_cast(bf16x8, a1);                                  \
    oacc = __builtin_amdgcn_mfma_f32_32x32x16_bf16(ap0, fv0, oacc, 0, 0, 0);            \
    oacc = __builtin_amdgcn_mfma_f32_32x32x16_bf16(ap1, fv1, oacc, 0, 0, 0);            \
    lacc = __builtin_amdgcn_mfma_f32_32x32x16_bf16(ap0, ones, lacc, 0, 0, 0);           \
    lacc = __builtin_amdgcn_mfma_f32_32x32x16_bf16(ap1, ones, lacc, 0, 0, 0);           \
} while (0)

    const int ntiles  = (NT / 128) / nseg;         // 16 @ jseg=2, 32 @ jseg=1
    const int j_begin = seg * ntiles * 128;

    // Prologue: stage tile 0 into buf 0.
    STAGE(0, j_begin);
    asm volatile("s_waitcnt vmcnt(0)" ::: "memory");
    __syncthreads();

    int buf = 0;
#pragma unroll 1
    for (int t = 0; t < ntiles; ++t) {
        if (t + 1 < ntiles) STAGE(buf ^ 1, j_begin + (t + 1) * 128);
        SUBTILE(buf, 0);
        SUBTILE(buf, 1);
        SUBTILE(buf, 2);
        SUBTILE(buf, 3);
        asm volatile("s_waitcnt vmcnt(0)" ::: "memory");
        __syncthreads();
        buf ^= 1;
    }

#undef STAGE
#undef SUBTILE

    if (nseg == 1) {
        // Direct epilogue: oacc/lacc rows q = 8*g4 + 4*hi + r, cols d = c32.
#pragma unroll
        for (int g4 = 0; g4 < 4; ++g4) {
#pragma unroll
            for (int r = 0; r < 4; ++r) {
                const int q = 8 * g4 + 4 * hi + r;
                ao[((size_t)(b * NT) + i0q + q) * CC + h * HD + c32] =
                    (__bf16)(oacc[4 * g4 + r] / lacc[4 * g4 + r]);
            }
        }
    } else {
        // Partial epilogue: PO [seg][bh][n][32] f32, PL [seg][bh][n] f32.
        float* po = PO + (((size_t)seg * NB * NHD + bh) * NT + i0q) * HD;
#pragma unroll
        for (int g4 = 0; g4 < 4; ++g4) {
#pragma unroll
            for (int r = 0; r < 4; ++r) {
                const int q = 8 * g4 + 4 * hi + r;
                po[(size_t)q * HD + c32] = oacc[4 * g4 + r];
            }
        }
        if (c32 == 0) {
            float* pl = PL + ((size_t)seg * NB * NHD + bh) * NT + i0q;
#pragma unroll
            for (int g4 = 0; g4 < 4; ++g4)
#pragma unroll
                for (int r = 0; r < 4; ++r)
                    pl[8 * g4 + 4 * hi + r] = lacc[4 * g4 + r];
        }
    }
}

// ---------------------------------------------------------------------------
// Kernel 3b: combine nseg partials: ao = (Sum O_s)/(Sum l_s), bf16.
// One thread = 4 consecutive d of one (bh, n). grid 2048 x 256.
// ---------------------------------------------------------------------------
__global__ __launch_bounds__(256) void comb_k(const float* __restrict__ PO,
                                              const float* __restrict__ PL,
                                              __bf16* __restrict__ ao,
                                              int nseg) {
    const int i = blockIdx.x * 256 + threadIdx.x;    // 0 .. 16*4096*8-1
    const int bh = i >> 15;                          // 8 groups * 4096 n
    const int rem = i & 32767;
    const int n = rem >> 3, g = rem & 7;
    const int b = bh >> 3, h = bh & 7;

    const size_t SEGO = (size_t)(NB * NHD) * NT * HD;
    const size_t SEGL = (size_t)(NB * NHD) * NT;
    const size_t o0i = (((size_t)bh) * NT + n) * HD + g * 4;
    const size_t li  = (size_t)bh * NT + n;

    f32x4 o = *(const f32x4_ma*)&PO[o0i];
    float l = PL[li];
#pragma unroll 3
    for (int s = 1; s < nseg; ++s) {
        o += *(const f32x4_ma*)&PO[(size_t)s * SEGO + o0i];
        l += PL[(size_t)s * SEGL + li];
    }

    bf16x4 pk;
#pragma unroll
    for (int r = 0; r < 4; ++r) pk[r] = (__bf16)(o[r] / l);
    *(bf16x4_ma*)&ao[((size_t)(b * NT) + n) * CC + h * HD + g * 4] = pk;
}

// ---------------------------------------------------------------------------
// Kernel 4: proj GEMM + residual (MFMA), F32 output, B-tile LDS-shared,
// 2-phase staging + early residual x-loads (R35 form).
// grid (NT/64, CC/64, NB), block 256.
// ---------------------------------------------------------------------------
__global__ __launch_bounds__(256) void proj_k(const __bf16* __restrict__ wp,
                                              const __bf16* __restrict__ ao,
                                              const float* __restrict__ x,
                                              float* __restrict__ out) {
    __shared__ __align__(16) __bf16 BF[4][8][512];   // [js][kc][lane*8] 32 KB

    const int lane = threadIdx.x & 63, wv = threadIdx.x >> 6;
    const int g = lane >> 4, c16 = lane & 15;
    const int b    = blockIdx.z;
    const int o0   = blockIdx.y * 64 + wv * 16;
    const int tok0 = blockIdx.x * 64;

    const __bf16* bsrc = ao + ((size_t)(b * NT + tok0 + wv * 16 + c16)) * CC + g * 8;
    // Stage half 0 (kc 0..3).
#pragma unroll
    for (int kc = 0; kc < 4; ++kc) {
        __builtin_amdgcn_global_load_lds(
            (const __attribute__((address_space(1))) void*)(bsrc + kc * 32),
            (__attribute__((address_space(3))) void*)&BF[wv][kc][0],
            16, 0, 0);
    }

    const __bf16* arow = wp + (size_t)(o0 + c16) * CC + g * 8;
    bf16x8 a[8];
#pragma unroll
    for (int kc = 0; kc < 8; ++kc) a[kc] = *(const bf16x8_ma*)(arow + kc * 32);

    // Early residual loads: x for the 16 epilogue adds, hidden under compute.
    float xres[4][4];
#pragma unroll
    for (int js = 0; js < 4; ++js) {
        const int tok = tok0 + js * 16 + c16;
#pragma unroll
        for (int r = 0; r < 4; ++r) {
            const int o = o0 + g * 4 + r;
            xres[js][r] = x[((size_t)(b * CC + o)) * NT + tok];
        }
    }

    __syncthreads();   // half 0 + A + x ready

    // Stage half 1 (kc 4..7) -- lands under the kc0..3 MFMAs.
#pragma unroll
    for (int kc = 4; kc < 8; ++kc) {
        __builtin_amdgcn_global_load_lds(
            (const __attribute__((address_space(1))) void*)(bsrc + kc * 32),
            (__attribute__((address_space(3))) void*)&BF[wv][kc][0],
            16, 0, 0);
    }

    f32x4 acc[4];
#pragma unroll
    for (int i = 0; i < 4; ++i) acc[i] = zero4();

#pragma unroll
    for (int kc = 0; kc < 4; ++kc) {
#pragma unroll
        for (int js = 0; js < 4; ++js) {
            bf16x8 bb = *(const bf16x8_ma*)&BF[js][kc][lane * 8];
            acc[js] = __builtin_amdgcn_mfma_f32_16x16x32_bf16(a[kc], bb, acc[js], 0, 0, 0);
        }
    }

    asm volatile("s_waitcnt vmcnt(0)" ::: "memory");
    __syncthreads();   // half 1 ready

#pragma unroll
    for (int kc = 4; kc < 8; ++kc) {
#pragma unroll
        for (int js = 0; js < 4; ++js) {
            bf16x8 bb = *(const bf16x8_ma*)&BF[js][kc][lane * 8];
            acc[js] = __builtin_amdgcn_mfma_f32_16x16x32_bf16(a[kc], bb, acc[js], 0, 0, 0);
        }
    }

#pragma unroll
    for (int js = 0; js < 4; ++js) {
        const int tok = tok0 + js * 16 + c16;
#pragma unroll
        for (int r = 0; r < 4; ++r) {
            const int o = o0 + g * 4 + r;
            const size_t idx = ((size_t)(b * CC + o)) * NT + tok;
            out[idx] = acc[js][r] + xres[js][r];
        }
    }
}

// ---------------------------------------------------------------------------
extern "C" void kernel_launch(void* const* d_in, const int* in_sizes, int n_in,
                              void* d_out, int out_size, void* d_ws, size_t ws_size,
                              hipStream_t stream) {
    const int SX  = NB * CC * NT;   // 2,097,152
    const int SW3 = 3 * CC * CC;    //   196,608
    const int SW1 = CC * CC;        //    65,536
    const size_t E = (size_t)SX;

    const float* x  = nullptr;
    const float* wq = nullptr;
    const float* wp = nullptr;
    for (int i = 0; i < n_in; ++i) {
        const int sz = in_sizes[i];
        if (sz == SX || sz == 2 * SX || sz == 4 * SX)           x  = (const float*)d_in[i];
        else if (sz == SW3 || sz == 2 * SW3 || sz == 4 * SW3)   wq = (const float*)d_in[i];
        else if (sz == SW1 || sz == 2 * SW1 || sz == 4 * SW1)   wp = (const float*)d_in[i];
    }
    if (!x || !wq || !wp) {
        x  = (const float*)d_in[0];
        wq = (const float*)d_in[1];
        wp = (const float*)d_in[2];
    }

    // Workspace (bf16 elements):
    __bf16* ws  = (__bf16*)d_ws;
    __bf16* wqb = ws;
    __bf16* wpb = wqb + SW3;
    __bf16* ao  = wpb + SW1;
    __bf16* qt  = ao + E;
    __bf16* kt  = qt + E;
    __bf16* vv  = kt + E;

    // Optional JSEG partial buffers (f32), appended after vv:
    const size_t baseB = (size_t)(SW3 + SW1) * 2 + 4 * E * 2;       // bytes used
    const size_t segoB = (size_t)NB * NHD * NT * HD * 4;            // 8.39 MB/seg
    const size_t seglB = (size_t)NB * NHD * NT * 4;                 // 0.26 MB/seg
    const int jseg = (ws_size >= baseB + 2 * (segoB + seglB)) ? 2 : 1;
    float* PO = (float*)((char*)d_ws + baseB);
    float* PL = (float*)((char*)d_ws + baseB + (size_t)jseg * segoB);

    float* out = (float*)d_out;

    convw_k<<<dim3((SW3 + SW1 + 255) / 256), 256, 0, stream>>>(wq, wqb, SW3, wp, wpb, SW1);
    qkv_k<<<dim3(NT / 64, 4, NB), 256, 0, stream>>>(wqb, x, qt, kt, vv);
    attn_k<<<dim3(NT / 128, NB * NHD, jseg), 256, 0, stream>>>(qt, kt, vv, ao, PO, PL);
    if (jseg > 1)
        comb_k<<<dim3((NB * NHD * NT * (HD / 4)) / 256), 256, 0, stream>>>(PO, PL, ao, jseg);
    proj_k<<<dim3(NT / 64, CC / 64, NB), 256, 0, stream>>>(wpb, ao, x, out);
}